// Round 6
// baseline (239.674 us; speedup 1.0000x reference)
//
#include <hip/hip_runtime.h>

namespace {
constexpr int   S_GRID   = 14;
constexpr int   CH       = 30;
constexpr float L_COORD  = 5.0f;
constexpr float L_NOOBJ  = 0.5f;
constexpr float BOX_EPS  = 1e-20f;
constexpr int   BLOCK    = 256;
constexpr int   CPT      = 2;     // cells per thread (60 floats = 15 float4)
constexpr int   NSLOT    = 256;   // hashed partial-sum slots
constexpr int   SLOT_STRIDE = 16; // floats between slots (64B -> own cache line)
}

// Per-cell loss; pv/tv must be indexed with compile-time constants (register
// residency — rule: no runtime indexing of unrolled arrays).
__device__ __forceinline__ float cell_loss(const float* __restrict__ pv,
                                           const float* __restrict__ tv)
{
    const float objf   = ((tv[4] + tv[9]) > 0.0f) ? 1.0f : 0.0f;
    const float noobjf = 1.0f - objf;

    const float d4 = pv[4] - tv[4];
    const float d9 = pv[9] - tv[9];
    const float no_obj = noobjf * (d4 * d4 + d9 * d9);

    float cls = 0.0f;
    #pragma unroll
    for (int j = 10; j < CH; ++j) {
        const float d = pv[j] - tv[j];
        cls += d * d;
    }
    cls *= objf;

    float iou[2];
    constexpr float invS = 1.0f / (float)S_GRID;
    #pragma unroll
    for (int b = 0; b < 2; ++b) {
        const float* bp = pv + 5 * b;
        const float* bt = tv + 5 * b;
        const float txc = bt[0] * invS, tyc = bt[1] * invS;
        const float tx1 = txc - 0.5f * bt[2], tx2 = txc + 0.5f * bt[2];
        const float ty1 = tyc - 0.5f * bt[3], ty2 = tyc + 0.5f * bt[3];
        const float pxc = bp[0] * invS, pyc = bp[1] * invS;
        const float px1 = pxc - 0.5f * bp[2], px2 = pxc + 0.5f * bp[2];
        const float py1 = pyc - 0.5f * bp[3], py2 = pyc + 0.5f * bp[3];
        const float iw = fmaxf(fminf(tx2, px2) - fmaxf(tx1, px1), 0.0f);
        const float ih = fmaxf(fminf(ty2, py2) - fmaxf(ty1, py1), 0.0f);
        const float inter  = iw * ih;
        const float area_t = (tx2 - tx1) * (ty2 - ty1);
        const float area_p = (px2 - px1) * (py2 - py1);
        iou[b] = inter / (area_t + area_p - inter);
    }

    // a0 = iou0 > iou1 ; a1 = float(a0) <= iou1
    const bool  a0   = iou[0] > iou[1];
    const bool  a1   = (a0 ? 1.0f : 0.0f) <= iou[1];
    const float sel0 = a0 ? 1.0f : 0.0f;
    const float sel1 = a1 ? 1.0f : 0.0f;

    float contain = 0.0f, regr = 0.0f;
    #pragma unroll
    for (int b = 0; b < 2; ++b) {
        const float w  = objf * (b == 0 ? sel0 : sel1);
        const float* bp = pv + 5 * b;
        const float* bt = tv + 5 * b;
        const float dc = bp[4] - iou[b];
        contain += w * dc * dc;
        const float dx  = bp[0] - bt[0];
        const float dy  = bp[1] - bt[1];
        const float dsw = sqrtf(bp[2] + BOX_EPS) - sqrtf(bt[2] + BOX_EPS);
        const float dsh = sqrtf(bp[3] + BOX_EPS) - sqrtf(bt[3] + BOX_EPS);
        regr += w * (dx * dx + dy * dy + dsw * dsw + dsh * dsh);
    }

    return L_COORD * regr + contain + L_NOOBJ * no_obj + cls;
}

// 2 cells per thread: 60 floats = 240B = 15 float4 per tensor, 16B-aligned.
// Halves L1 transactions per cell vs float2/cell (the R5-measured limiter:
// ~64 line-split transactions per wave-load regardless of width, so wider
// loads -> fewer instructions -> fewer transactions per byte).
__global__ __launch_bounds__(BLOCK) void yolo_main_kernel(
    const float* __restrict__ pred,
    const float* __restrict__ tgt,
    float* __restrict__ partial)
{
    __shared__ float wsum[BLOCK / 64];

    const int tid = threadIdx.x;
    const size_t pair = (size_t)blockIdx.x * BLOCK + tid;  // 2-cell group idx

    const float4* gp4 = reinterpret_cast<const float4*>(pred) + pair * 15;
    const float4* gt4 = reinterpret_cast<const float4*>(tgt) + pair * 15;

    float pv[CPT * CH], tv[CPT * CH];
    #pragma unroll
    for (int j = 0; j < 15; ++j) {
        const float4 a = gp4[j];
        pv[4 * j] = a.x; pv[4 * j + 1] = a.y;
        pv[4 * j + 2] = a.z; pv[4 * j + 3] = a.w;
        const float4 b = gt4[j];
        tv[4 * j] = b.x; tv[4 * j + 1] = b.y;
        tv[4 * j + 2] = b.z; tv[4 * j + 3] = b.w;
    }

    float acc = 0.0f;
    #pragma unroll
    for (int c = 0; c < CPT; ++c)
        acc += cell_loss(pv + c * CH, tv + c * CH);

    // ---- block reduction: per-wave shuffles, cross-wave via LDS
    #pragma unroll
    for (int off = 32; off > 0; off >>= 1)
        acc += __shfl_down(acc, off, 64);
    const int lane = tid & 63;
    const int wid  = tid >> 6;
    if (lane == 0) wsum[wid] = acc;
    __syncthreads();
    if (tid == 0) {
        const float s = (wsum[0] + wsum[1]) + (wsum[2] + wsum[3]);
        atomicAdd(&partial[(blockIdx.x & (NSLOT - 1)) * SLOT_STRIDE], s);
    }
}

// 256 partial slots -> single scalar output (plain store, no atomic)
__global__ __launch_bounds__(NSLOT) void yolo_finalize_kernel(
    const float* __restrict__ partial,
    float* __restrict__ out,
    float inv_n)
{
    __shared__ float wsum[NSLOT / 64];
    const int tid = threadIdx.x;
    float v = partial[tid * SLOT_STRIDE];
    #pragma unroll
    for (int off = 32; off > 0; off >>= 1)
        v += __shfl_down(v, off, 64);
    const int lane = tid & 63;
    const int wid  = tid >> 6;
    if (lane == 0) wsum[wid] = v;
    __syncthreads();
    if (tid == 0)
        out[0] = ((wsum[0] + wsum[1]) + (wsum[2] + wsum[3])) * inv_n;
}

extern "C" void kernel_launch(void* const* d_in, const int* in_sizes, int n_in,
                              void* d_out, int out_size, void* d_ws, size_t ws_size,
                              hipStream_t stream) {
    const float* pred = (const float*)d_in[0];
    const float* tgt  = (const float*)d_in[1];
    float* out     = (float*)d_out;
    float* partial = (float*)d_ws;    // NSLOT*SLOT_STRIDE floats = 16 KB

    const int ncells  = in_sizes[0] / CH;             // 4096*14*14 = 802816
    const int n_batch = ncells / (S_GRID * S_GRID);   // 4096
    const int grid    = ncells / (BLOCK * CPT);       // 1568 (exact)

    // d_ws is re-poisoned to 0xAA before every timed launch
    hipMemsetAsync(partial, 0, NSLOT * SLOT_STRIDE * sizeof(float), stream);
    yolo_main_kernel<<<grid, BLOCK, 0, stream>>>(pred, tgt, partial);
    yolo_finalize_kernel<<<1, NSLOT, 0, stream>>>(partial, out,
                                                  1.0f / (float)n_batch);
}

// Round 7
// 211.944 us; speedup vs baseline: 1.1308x; 1.1308x over previous
//
#include <hip/hip_runtime.h>

namespace {
constexpr int   S_GRID   = 14;
constexpr int   CH       = 30;
constexpr float L_COORD  = 5.0f;
constexpr float L_NOOBJ  = 0.5f;
constexpr float BOX_EPS  = 1e-20f;
constexpr int   BLOCK    = 256;
constexpr int   TILE     = 256;      // cells per block, 1 per thread
constexpr int   NV4      = TILE * CH / 4;   // 1920 float4 per tensor-tile
constexpr int   NSLOT    = 256;      // hashed partial-sum slots
constexpr int   SLOT_STRIDE = 16;    // floats between slots (64B lines)
}

// Per-cell loss (compile-time indexing only).
__device__ __forceinline__ float cell_loss(const float* __restrict__ pv,
                                           const float* __restrict__ tv)
{
    const float objf   = ((tv[4] + tv[9]) > 0.0f) ? 1.0f : 0.0f;
    const float noobjf = 1.0f - objf;

    const float d4 = pv[4] - tv[4];
    const float d9 = pv[9] - tv[9];
    const float no_obj = noobjf * (d4 * d4 + d9 * d9);

    float cls = 0.0f;
    #pragma unroll
    for (int j = 10; j < CH; ++j) {
        const float d = pv[j] - tv[j];
        cls += d * d;
    }
    cls *= objf;

    float iou[2];
    constexpr float invS = 1.0f / (float)S_GRID;
    #pragma unroll
    for (int b = 0; b < 2; ++b) {
        const float* bp = pv + 5 * b;
        const float* bt = tv + 5 * b;
        const float txc = bt[0] * invS, tyc = bt[1] * invS;
        const float tx1 = txc - 0.5f * bt[2], tx2 = txc + 0.5f * bt[2];
        const float ty1 = tyc - 0.5f * bt[3], ty2 = tyc + 0.5f * bt[3];
        const float pxc = bp[0] * invS, pyc = bp[1] * invS;
        const float px1 = pxc - 0.5f * bp[2], px2 = pxc + 0.5f * bp[2];
        const float py1 = pyc - 0.5f * bp[3], py2 = pyc + 0.5f * bp[3];
        const float iw = fmaxf(fminf(tx2, px2) - fmaxf(tx1, px1), 0.0f);
        const float ih = fmaxf(fminf(ty2, py2) - fmaxf(ty1, py1), 0.0f);
        const float inter  = iw * ih;
        const float area_t = (tx2 - tx1) * (ty2 - ty1);
        const float area_p = (px2 - px1) * (py2 - py1);
        iou[b] = inter / (area_t + area_p - inter);
    }

    // a0 = iou0 > iou1 ; a1 = float(a0) <= iou1
    const bool  a0   = iou[0] > iou[1];
    const bool  a1   = (a0 ? 1.0f : 0.0f) <= iou[1];
    const float sel0 = a0 ? 1.0f : 0.0f;
    const float sel1 = a1 ? 1.0f : 0.0f;

    float contain = 0.0f, regr = 0.0f;
    #pragma unroll
    for (int b = 0; b < 2; ++b) {
        const float w  = objf * (b == 0 ? sel0 : sel1);
        const float* bp = pv + 5 * b;
        const float* bt = tv + 5 * b;
        const float dc = bp[4] - iou[b];
        contain += w * dc * dc;
        const float dx  = bp[0] - bt[0];
        const float dy  = bp[1] - bt[1];
        const float dsw = sqrtf(bp[2] + BOX_EPS) - sqrtf(bt[2] + BOX_EPS);
        const float dsh = sqrtf(bp[3] + BOX_EPS) - sqrtf(bt[3] + BOX_EPS);
        regr += w * (dx * dx + dy * dy + dsw * dsw + dsh * dsh);
    }

    return L_COORD * regr + contain + L_NOOBJ * no_obj + cls;
}

// Coalesced global->LDS staging through ONE 30KiB buffer used twice:
// phase A stages pred, threads pull their cell into registers; phase B
// re-stages tgt into the same buffer. 30.8KiB LDS -> 5 blocks/CU =
// 20 waves/CU (vs 2 blocks/CU in the 61KiB variant). Wave-coalesced
// loads keep line reuse inside a single instruction (no AoS L1 thrash:
// R6 showed AoS direct loads over-fetch 272MB vs 98MB). Holding pv[] in
// registers across phase B forces real VGPR allocation (kills the
// compiler's global-load rematerialization seen at VGPR_Count=36).
__global__ __launch_bounds__(BLOCK) void yolo_main_kernel(
    const float* __restrict__ pred,
    const float* __restrict__ tgt,
    float* __restrict__ partial)
{
    __shared__ float sbuf[TILE * CH];   // 30720 B, staged twice
    __shared__ float wsum[BLOCK / 64];

    const int tid = threadIdx.x;
    const size_t base = (size_t)blockIdx.x * (TILE * CH);
    float4* s4 = reinterpret_cast<float4*>(sbuf);

    // ---- phase A: stage pred tile (coalesced float4), read cell into regs
    {
        const float4* g4 = reinterpret_cast<const float4*>(pred + base);
        #pragma unroll
        for (int i = 0; i < 8; ++i) {           // 1920 = 7.5 * 256
            const int idx = tid + i * BLOCK;
            if (idx < NV4) s4[idx] = g4[idx];
        }
    }
    __syncthreads();

    float pv[CH];
    {
        const float2* row = reinterpret_cast<const float2*>(sbuf + tid * CH);
        #pragma unroll
        for (int j = 0; j < CH / 2; ++j) {
            const float2 a = row[j];
            pv[2 * j] = a.x; pv[2 * j + 1] = a.y;
        }
    }
    __syncthreads();   // all reads of pred done before overwrite

    // ---- phase B: stage tgt tile into the same buffer
    {
        const float4* g4 = reinterpret_cast<const float4*>(tgt + base);
        #pragma unroll
        for (int i = 0; i < 8; ++i) {
            const int idx = tid + i * BLOCK;
            if (idx < NV4) s4[idx] = g4[idx];
        }
    }
    __syncthreads();

    float tv[CH];
    {
        const float2* row = reinterpret_cast<const float2*>(sbuf + tid * CH);
        #pragma unroll
        for (int j = 0; j < CH / 2; ++j) {
            const float2 b = row[j];
            tv[2 * j] = b.x; tv[2 * j + 1] = b.y;
        }
    }

    float acc = cell_loss(pv, tv);

    // ---- block reduction: per-wave shuffles, cross-wave via LDS
    #pragma unroll
    for (int off = 32; off > 0; off >>= 1)
        acc += __shfl_down(acc, off, 64);
    const int lane = tid & 63;
    const int wid  = tid >> 6;
    if (lane == 0) wsum[wid] = acc;
    __syncthreads();
    if (tid == 0) {
        const float s = (wsum[0] + wsum[1]) + (wsum[2] + wsum[3]);
        atomicAdd(&partial[(blockIdx.x & (NSLOT - 1)) * SLOT_STRIDE], s);
    }
}

// 256 partial slots -> single scalar output (plain store, no atomic)
__global__ __launch_bounds__(NSLOT) void yolo_finalize_kernel(
    const float* __restrict__ partial,
    float* __restrict__ out,
    float inv_n)
{
    __shared__ float wsum[NSLOT / 64];
    const int tid = threadIdx.x;
    float v = partial[tid * SLOT_STRIDE];
    #pragma unroll
    for (int off = 32; off > 0; off >>= 1)
        v += __shfl_down(v, off, 64);
    const int lane = tid & 63;
    const int wid  = tid >> 6;
    if (lane == 0) wsum[wid] = v;
    __syncthreads();
    if (tid == 0)
        out[0] = ((wsum[0] + wsum[1]) + (wsum[2] + wsum[3])) * inv_n;
}

extern "C" void kernel_launch(void* const* d_in, const int* in_sizes, int n_in,
                              void* d_out, int out_size, void* d_ws, size_t ws_size,
                              hipStream_t stream) {
    const float* pred = (const float*)d_in[0];
    const float* tgt  = (const float*)d_in[1];
    float* out     = (float*)d_out;
    float* partial = (float*)d_ws;    // NSLOT*SLOT_STRIDE floats = 16 KB

    const int ncells  = in_sizes[0] / CH;             // 4096*14*14 = 802816
    const int n_batch = ncells / (S_GRID * S_GRID);   // 4096
    const int grid    = ncells / TILE;                // 3136 (exact)

    // d_ws is re-poisoned to 0xAA before every timed launch
    hipMemsetAsync(partial, 0, NSLOT * SLOT_STRIDE * sizeof(float), stream);
    yolo_main_kernel<<<grid, BLOCK, 0, stream>>>(pred, tgt, partial);
    yolo_finalize_kernel<<<1, NSLOT, 0, stream>>>(partial, out,
                                                  1.0f / (float)n_batch);
}

// Round 10
// 206.167 us; speedup vs baseline: 1.1625x; 1.0280x over previous
//
#include <hip/hip_runtime.h>

namespace {
constexpr int   S_GRID   = 14;
constexpr int   CH       = 30;
constexpr float L_COORD  = 5.0f;
constexpr float L_NOOBJ  = 0.5f;
constexpr float BOX_EPS  = 1e-20f;
constexpr int   BLOCK    = 256;            // 4 waves
constexpr int   WAVES_PB = BLOCK / 64;
constexpr int   WTILE    = 64;             // cells per wave-tile
constexpr int   WFLOATS  = WTILE * CH;     // 1920 floats per tensor per tile
constexpr int   NCHUNK   = WFLOATS / 2 / 64; // 15 float2 chunks per lane per tensor
constexpr int   GRID     = 512;            // 2 blocks/CU exactly
constexpr int   NWAVES   = GRID * WAVES_PB;  // 2048
constexpr int   NSLOT    = 256;
constexpr int   SLOT_STRIDE = 16;          // 64B-separated partial slots
}

// Per-cell loss (compile-time indexing only; exact transcription of reference).
__device__ __forceinline__ float cell_loss(const float* __restrict__ pv,
                                           const float* __restrict__ tv)
{
    const float objf   = ((tv[4] + tv[9]) > 0.0f) ? 1.0f : 0.0f;
    const float noobjf = 1.0f - objf;

    const float d4 = pv[4] - tv[4];
    const float d9 = pv[9] - tv[9];
    const float no_obj = noobjf * (d4 * d4 + d9 * d9);

    float cls = 0.0f;
    #pragma unroll
    for (int j = 10; j < CH; ++j) {
        const float d = pv[j] - tv[j];
        cls += d * d;
    }
    cls *= objf;

    float iou[2];
    constexpr float invS = 1.0f / (float)S_GRID;
    #pragma unroll
    for (int b = 0; b < 2; ++b) {
        const float* bp = pv + 5 * b;
        const float* bt = tv + 5 * b;
        const float txc = bt[0] * invS, tyc = bt[1] * invS;
        const float tx1 = txc - 0.5f * bt[2], tx2 = txc + 0.5f * bt[2];
        const float ty1 = tyc - 0.5f * bt[3], ty2 = tyc + 0.5f * bt[3];
        const float pxc = bp[0] * invS, pyc = bp[1] * invS;
        const float px1 = pxc - 0.5f * bp[2], px2 = pxc + 0.5f * bp[2];
        const float py1 = pyc - 0.5f * bp[3], py2 = pyc + 0.5f * bp[3];
        const float iw = fmaxf(fminf(tx2, px2) - fmaxf(tx1, px1), 0.0f);
        const float ih = fmaxf(fminf(ty2, py2) - fmaxf(ty1, py1), 0.0f);
        const float inter  = iw * ih;
        const float area_t = (tx2 - tx1) * (ty2 - ty1);
        const float area_p = (px2 - px1) * (py2 - py1);
        iou[b] = inter / (area_t + area_p - inter);
    }

    // a0 = iou0 > iou1 ; a1 = float(a0) <= iou1
    const bool  a0   = iou[0] > iou[1];
    const bool  a1   = (a0 ? 1.0f : 0.0f) <= iou[1];
    const float sel0 = a0 ? 1.0f : 0.0f;
    const float sel1 = a1 ? 1.0f : 0.0f;

    float contain = 0.0f, regr = 0.0f;
    #pragma unroll
    for (int b = 0; b < 2; ++b) {
        const float w  = objf * (b == 0 ? sel0 : sel1);
        const float* bp = pv + 5 * b;
        const float* bt = tv + 5 * b;
        const float dc = bp[4] - iou[b];
        contain += w * dc * dc;
        const float dx  = bp[0] - bt[0];
        const float dy  = bp[1] - bt[1];
        const float dsw = sqrtf(bp[2] + BOX_EPS) - sqrtf(bt[2] + BOX_EPS);
        const float dsh = sqrtf(bp[3] + BOX_EPS) - sqrtf(bt[3] + BOX_EPS);
        regr += w * (dx * dx + dy * dy + dsw * dsw + dsh * dsh);
    }

    return L_COORD * regr + contain + L_NOOBJ * no_obj + cls;
}

// Barrier-free wave-autonomous streaming: each wave owns a private LDS region
// (15.4 KiB) and grid-strides over 64-cell tiles. Per tile: reg-staged
// coalesced float2 loads -> ds_write (linear mirror of global layout) ->
// prefetch next tile -> ds_read own cell row -> compute. No __syncthreads in
// the loop, so vmcnt is never drained: the next tile's 30 loads stay in
// flight under the current tile's compute (the R1/R5/R7 common limiter was
// load-issue duty cycle, all plateauing at ~2.5 TB/s delivered).
__global__ __launch_bounds__(BLOCK, 2) void yolo_main_kernel(
    const float* __restrict__ pred,
    const float* __restrict__ tgt,
    float* __restrict__ partial,
    int ntiles)
{
    __shared__ float sbuf[WAVES_PB][2 * WFLOATS];  // [wave][pred|tgt] 61440 B
    __shared__ float wsum[WAVES_PB];

    const int tid  = threadIdx.x;
    const int lane = tid & 63;
    const int wid  = tid >> 6;
    const int wglob = blockIdx.x * WAVES_PB + wid;

    float2* wp2 = reinterpret_cast<float2*>(sbuf[wid]);            // pred region
    float2* wt2 = reinterpret_cast<float2*>(sbuf[wid] + WFLOATS);  // tgt region

    float2 bp[NCHUNK], bt[NCHUNK];   // reg-staged tile (in-flight buffer)
    float  acc = 0.0f;

    int t = wglob;
    if (t < ntiles) {
        const float2* gp = reinterpret_cast<const float2*>(pred) + (size_t)t * (WFLOATS / 2);
        const float2* gt = reinterpret_cast<const float2*>(tgt)  + (size_t)t * (WFLOATS / 2);
        #pragma unroll
        for (int j = 0; j < NCHUNK; ++j) {
            bp[j] = gp[j * 64 + lane];
            bt[j] = gt[j * 64 + lane];
        }
    }

    while (t < ntiles) {
        // ---- stage tile t into this wave's LDS region (linear mirror)
        #pragma unroll
        for (int j = 0; j < NCHUNK; ++j) {
            wp2[j * 64 + lane] = bp[j];
            wt2[j * 64 + lane] = bt[j];
        }

        // ---- issue next tile's loads (in flight during compute below)
        const int tn = t + NWAVES;
        if (tn < ntiles) {
            const float2* gp = reinterpret_cast<const float2*>(pred) + (size_t)tn * (WFLOATS / 2);
            const float2* gt = reinterpret_cast<const float2*>(tgt)  + (size_t)tn * (WFLOATS / 2);
            #pragma unroll
            for (int j = 0; j < NCHUNK; ++j) {
                bp[j] = gp[j * 64 + lane];
                bt[j] = gt[j * 64 + lane];
            }
        }

        // ---- read own cell (lane = cell within tile) and compute
        float pv[CH], tv[CH];
        {
            const float2* rowp = reinterpret_cast<const float2*>(sbuf[wid] + lane * CH);
            const float2* rowt = reinterpret_cast<const float2*>(sbuf[wid] + WFLOATS + lane * CH);
            #pragma unroll
            for (int j = 0; j < CH / 2; ++j) {
                const float2 a = rowp[j];
                pv[2 * j] = a.x; pv[2 * j + 1] = a.y;
                const float2 b = rowt[j];
                tv[2 * j] = b.x; tv[2 * j + 1] = b.y;
            }
        }
        acc += cell_loss(pv, tv);

        t = tn;
    }

    // ---- wave reduce, then block reduce (single barrier per block)
    #pragma unroll
    for (int off = 32; off > 0; off >>= 1)
        acc += __shfl_down(acc, off, 64);
    if (lane == 0) wsum[wid] = acc;
    __syncthreads();
    if (tid == 0) {
        const float s = (wsum[0] + wsum[1]) + (wsum[2] + wsum[3]);
        atomicAdd(&partial[(blockIdx.x & (NSLOT - 1)) * SLOT_STRIDE], s);
    }
}

// 256 partial slots -> single scalar output (plain store, no atomic)
__global__ __launch_bounds__(NSLOT) void yolo_finalize_kernel(
    const float* __restrict__ partial,
    float* __restrict__ out,
    float inv_n)
{
    __shared__ float wsum[NSLOT / 64];
    const int tid = threadIdx.x;
    float v = partial[tid * SLOT_STRIDE];
    #pragma unroll
    for (int off = 32; off > 0; off >>= 1)
        v += __shfl_down(v, off, 64);
    const int lane = tid & 63;
    const int wid  = tid >> 6;
    if (lane == 0) wsum[wid] = v;
    __syncthreads();
    if (tid == 0)
        out[0] = ((wsum[0] + wsum[1]) + (wsum[2] + wsum[3])) * inv_n;
}

extern "C" void kernel_launch(void* const* d_in, const int* in_sizes, int n_in,
                              void* d_out, int out_size, void* d_ws, size_t ws_size,
                              hipStream_t stream) {
    const float* pred = (const float*)d_in[0];
    const float* tgt  = (const float*)d_in[1];
    float* out     = (float*)d_out;
    float* partial = (float*)d_ws;    // NSLOT*SLOT_STRIDE floats = 16 KB

    const int ncells  = in_sizes[0] / CH;             // 4096*14*14 = 802816
    const int n_batch = ncells / (S_GRID * S_GRID);   // 4096
    const int ntiles  = ncells / WTILE;               // 12544 (exact)

    // d_ws is re-poisoned to 0xAA before every timed launch
    hipMemsetAsync(partial, 0, NSLOT * SLOT_STRIDE * sizeof(float), stream);
    yolo_main_kernel<<<GRID, BLOCK, 0, stream>>>(pred, tgt, partial, ntiles);
    yolo_finalize_kernel<<<1, NSLOT, 0, stream>>>(partial, out,
                                                  1.0f / (float)n_batch);
}